// Round 1
// baseline (63.434 us; speedup 1.0000x reference)
//
#include <hip/hip_runtime.h>
#include <cfloat>

constexpr int BDIM = 256;
constexpr int NPTS = 8192;
constexpr int KSEL = 16;
constexpr int PD_  = 16;
constexpr int DIN  = 20;
constexpr int HID  = 128;
constexpr int DOUT = 256;

__device__ __forceinline__ bool better(float d1, int i1, float d2, int i2) {
    // strict total order: smaller distance wins, ties broken by smaller index
    return (d1 < d2) || (d1 == d2 && i1 < i2);
}

__global__ __launch_bounds__(BDIM) void encoder_kernel(
    const float* __restrict__ lg,      // (2,)
    const float* __restrict__ coords,  // (B, N, 3)
    const float* __restrict__ params,  // (B, N, 16)
    const float* __restrict__ W1, const float* __restrict__ b1,
    const float* __restrict__ W2, const float* __restrict__ b2,
    const float* __restrict__ W3, const float* __restrict__ b3,
    float* __restrict__ out)           // (B, 256)
{
    __shared__ float red_d[BDIM];
    __shared__ int   red_i[BDIM];
    __shared__ int   sel[KSEL];
    __shared__ float xvec[DIN];
    __shared__ float h1[HID];
    __shared__ float h2[HID];

    const int b   = blockIdx.x;
    const int tid = threadIdx.x;
    const float lg0 = lg[0];
    const float lg1 = lg[1];

    // ---- Phase 1: distances for 32 points/thread, kept in registers ----
    // group g covers points 4g..4g+3 (floats 12g..12g+11), read as 3x float4
    const float4* c4 = reinterpret_cast<const float4*>(coords + (size_t)b * NPTS * 3);

    float dd[32];
    #pragma unroll
    for (int it = 0; it < 8; ++it) {
        const int g = it * BDIM + tid;
        const float4 qa = c4[3 * g + 0];
        const float4 qb = c4[3 * g + 1];
        const float4 qc = c4[3 * g + 2];
        const float px[4] = {qa.x, qa.w, qb.z, qc.y};
        const float py[4] = {qa.y, qb.x, qb.w, qc.z};
        #pragma unroll
        for (int j = 0; j < 4; ++j) {
            // match numpy: t0*t0 + t1*t1, each op rounded fp32, NO fma contraction
            const float t0 = __fsub_rn(lg0, px[j]);
            const float t1 = __fsub_rn(lg1, py[j]);
            dd[it * 4 + j] = __fadd_rn(__fmul_rn(t0, t0), __fmul_rn(t1, t1));
        }
    }
    // point index for local slot l: n = (l>>2)*1024 + 4*tid + (l&3)

    // ---- Phase 2: top-16 selection (16 rounds of block argmin) ----
    unsigned int removed = 0u;
    float lmd = FLT_MAX;
    int   lmi = 0x7fffffff;
    #pragma unroll
    for (int l = 0; l < 32; ++l) {
        const int n = ((l >> 2) << 10) + (tid << 2) + (l & 3);
        if (better(dd[l], n, lmd, lmi)) { lmd = dd[l]; lmi = n; }
    }

    for (int r = 0; r < KSEL; ++r) {
        __syncthreads();                  // protect red arrays from prior round reads
        red_d[tid] = lmd;
        red_i[tid] = lmi;
        __syncthreads();
        #pragma unroll
        for (int s = BDIM / 2; s > 0; s >>= 1) {
            if (tid < s) {
                if (better(red_d[tid + s], red_i[tid + s], red_d[tid], red_i[tid])) {
                    red_d[tid] = red_d[tid + s];
                    red_i[tid] = red_i[tid + s];
                }
            }
            __syncthreads();
        }
        const int wi = red_i[0];          // winning global point index (unique)
        if (tid == 0) sel[r] = wi;
        // owner thread removes it and recomputes its local min (register rescan)
        if (((wi >> 2) & 255) == tid) {
            removed |= 1u << (((wi >> 10) << 2) | (wi & 3));
            lmd = FLT_MAX; lmi = 0x7fffffff;
            #pragma unroll
            for (int l = 0; l < 32; ++l) {
                const int n = ((l >> 2) << 10) + (tid << 2) + (l & 3);
                const float dl = (removed & (1u << l)) ? FLT_MAX : dd[l];
                if (better(dl, n, lmd, lmi)) { lmd = dl; lmi = n; }
            }
        }
    }
    __syncthreads();

    // ---- Phase 3: means over the 16 selected neighbors -> 20-dim feature ----
    if (tid < DIN) {
        float v;
        if (tid < 2) {
            v = lg[tid];
        } else if (tid < 4) {
            const int c = tid - 2;
            float s = 0.f;
            for (int k = 0; k < KSEL; ++k)
                s += coords[(size_t)b * NPTS * 3 + (size_t)sel[k] * 3 + c];
            v = s * (1.f / 16.f);
        } else {
            const int p = tid - 4;
            float s = 0.f;
            for (int k = 0; k < KSEL; ++k)
                s += params[((size_t)b * NPTS + sel[k]) * PD_ + p];
            v = s * (1.f / 16.f);
        }
        xvec[tid] = v;
    }
    __syncthreads();

    // ---- Phase 4: MLP 20 -> 128 -> 128 -> 256 (fp32, weights L2-resident) ----
    if (tid < HID) {
        float acc = b1[tid];
        #pragma unroll
        for (int i = 0; i < DIN; ++i) acc = fmaf(xvec[i], W1[i * HID + tid], acc);
        h1[tid] = fmaxf(acc, 0.f);
    }
    __syncthreads();
    if (tid < HID) {
        float acc = b2[tid];
        #pragma unroll 8
        for (int i = 0; i < HID; ++i) acc = fmaf(h1[i], W2[i * HID + tid], acc);
        h2[tid] = fmaxf(acc, 0.f);
    }
    __syncthreads();
    {
        float acc = b3[tid];
        #pragma unroll 8
        for (int i = 0; i < HID; ++i) acc = fmaf(h2[i], W3[i * DOUT + tid], acc);
        out[(size_t)b * DOUT + tid] = acc;
    }
}

extern "C" void kernel_launch(void* const* d_in, const int* in_sizes, int n_in,
                              void* d_out, int out_size, void* d_ws, size_t ws_size,
                              hipStream_t stream) {
    const float* lg     = (const float*)d_in[0];
    const float* coords = (const float*)d_in[1];
    const float* params = (const float*)d_in[2];
    const float* W1     = (const float*)d_in[3];
    const float* b1     = (const float*)d_in[4];
    const float* W2     = (const float*)d_in[5];
    const float* b2     = (const float*)d_in[6];
    const float* W3     = (const float*)d_in[7];
    const float* b3     = (const float*)d_in[8];
    float* out          = (float*)d_out;

    const int B = in_sizes[1] / (NPTS * 3);   // 1024
    encoder_kernel<<<dim3(B), dim3(BDIM), 0, stream>>>(
        lg, coords, params, W1, b1, W2, b2, W3, b3, out);
}

// Round 2
// 58.318 us; speedup vs baseline: 1.0877x; 1.0877x over previous
//
#include <hip/hip_runtime.h>
#include <cfloat>

constexpr int BDIM = 256;
constexpr int NPTS = 8192;
constexpr int KSEL = 16;
constexpr int PD_  = 16;
constexpr int DIN  = 20;
constexpr int HID  = 128;
constexpr int DOUT = 256;

__device__ __forceinline__ unsigned long long mkkey(float d, int n) {
    return ((unsigned long long)__float_as_uint(d) << 32) | (unsigned int)n;
}
__device__ __forceinline__ unsigned long long umin64(unsigned long long a,
                                                     unsigned long long b) {
    return a < b ? a : b;
}

__global__ __launch_bounds__(BDIM) void encoder_kernel(
    const float* __restrict__ lg,      // (2,)
    const float* __restrict__ coords,  // (B, N, 3)
    const float* __restrict__ params,  // (B, N, 16)
    const float* __restrict__ W1, const float* __restrict__ b1,
    const float* __restrict__ W2, const float* __restrict__ b2,
    const float* __restrict__ W3, const float* __restrict__ b3,
    float* __restrict__ out)           // (B, 256)
{
    __shared__ unsigned long long wmin[2][4];  // double-buffered per-wave minima
    __shared__ int   sel[KSEL];
    __shared__ float xvec[DIN];
    __shared__ float h1[HID];
    __shared__ float h2[HID];

    const int b    = blockIdx.x;
    const int tid  = threadIdx.x;
    const int lane = tid & 63;
    const int wid  = tid >> 6;
    const float lg0 = lg[0];
    const float lg1 = lg[1];

    // ---- Phase 1: distances for 32 points/thread, packed (dist|idx) keys ----
    const float4* c4 = reinterpret_cast<const float4*>(coords + (size_t)b * NPTS * 3);

    unsigned long long kk[32];
    #pragma unroll
    for (int it = 0; it < 8; ++it) {
        const int g = it * BDIM + tid;
        const float4 qa = c4[3 * g + 0];
        const float4 qb = c4[3 * g + 1];
        const float4 qc = c4[3 * g + 2];
        const float px[4] = {qa.x, qa.w, qb.z, qc.y};
        const float py[4] = {qa.y, qb.x, qb.w, qc.z};
        #pragma unroll
        for (int j = 0; j < 4; ++j) {
            // match numpy rounding: sub, sub, mul, mul, add — no fma contraction
            const float t0 = __fsub_rn(lg0, px[j]);
            const float t1 = __fsub_rn(lg1, py[j]);
            const float d  = __fadd_rn(__fmul_rn(t0, t0), __fmul_rn(t1, t1));
            const int   n  = (it << 10) + (tid << 2) + j;   // global point index
            kk[it * 4 + j] = mkkey(d, n);
        }
    }

    // per-thread min (tree over registers, non-destructive)
    unsigned long long lkey;
    {
        unsigned long long t[16];
        #pragma unroll
        for (int l = 0; l < 16; ++l) t[l] = umin64(kk[2 * l], kk[2 * l + 1]);
        #pragma unroll
        for (int s = 8; s > 0; s >>= 1)
            #pragma unroll
            for (int l = 0; l < 16; ++l) if (l < s) t[l] = umin64(t[l], t[l + s]);
        lkey = t[0];
    }

    // ---- Phase 2: top-16 via 16 rounds of (wave butterfly + 4-way LDS min) ----
    for (int r = 0; r < KSEL; ++r) {
        unsigned long long w = lkey;
        #pragma unroll
        for (int off = 32; off > 0; off >>= 1)
            w = umin64(w, __shfl_xor(w, off, 64));
        if (lane == 0) wmin[r & 1][wid] = w;
        __syncthreads();
        unsigned long long wall = umin64(umin64(wmin[r & 1][0], wmin[r & 1][1]),
                                         umin64(wmin[r & 1][2], wmin[r & 1][3]));
        const int wi = (int)(unsigned int)wall;   // winning global point index
        if (tid == 0) sel[r] = wi;
        if (((wi >> 2) & 255) == tid) {           // owner removes & rescans
            kk[((wi >> 10) << 2) | (wi & 3)] = ~0ull;
            unsigned long long m = kk[0];
            #pragma unroll
            for (int l = 1; l < 32; ++l) m = umin64(m, kk[l]);
            lkey = m;
        }
    }
    __syncthreads();

    // ---- Phase 3: means over the 16 selected neighbors -> 20-dim feature ----
    if (tid < DIN) {
        float v;
        if (tid < 2) {
            v = lg[tid];
        } else if (tid < 4) {
            const int c = tid - 2;
            float s = 0.f;
            for (int k = 0; k < KSEL; ++k)
                s += coords[(size_t)b * NPTS * 3 + (size_t)sel[k] * 3 + c];
            v = s * (1.f / 16.f);
        } else {
            const int p = tid - 4;
            float s = 0.f;
            for (int k = 0; k < KSEL; ++k)
                s += params[((size_t)b * NPTS + sel[k]) * PD_ + p];
            v = s * (1.f / 16.f);
        }
        xvec[tid] = v;
    }
    __syncthreads();

    // ---- Phase 4: MLP 20 -> 128 -> 128 -> 256 (fp32, weights L2-resident) ----
    if (tid < HID) {
        float acc = b1[tid];
        #pragma unroll
        for (int i = 0; i < DIN; ++i) acc = fmaf(xvec[i], W1[i * HID + tid], acc);
        h1[tid] = fmaxf(acc, 0.f);
    }
    __syncthreads();
    if (tid < HID) {
        float acc = b2[tid];
        #pragma unroll 8
        for (int i = 0; i < HID; ++i) acc = fmaf(h1[i], W2[i * HID + tid], acc);
        h2[tid] = fmaxf(acc, 0.f);
    }
    __syncthreads();
    {
        float acc = b3[tid];
        #pragma unroll 8
        for (int i = 0; i < HID; ++i) acc = fmaf(h2[i], W3[i * DOUT + tid], acc);
        out[(size_t)b * DOUT + tid] = acc;
    }
}

extern "C" void kernel_launch(void* const* d_in, const int* in_sizes, int n_in,
                              void* d_out, int out_size, void* d_ws, size_t ws_size,
                              hipStream_t stream) {
    const float* lg     = (const float*)d_in[0];
    const float* coords = (const float*)d_in[1];
    const float* params = (const float*)d_in[2];
    const float* W1     = (const float*)d_in[3];
    const float* b1     = (const float*)d_in[4];
    const float* W2     = (const float*)d_in[5];
    const float* b2     = (const float*)d_in[6];
    const float* W3     = (const float*)d_in[7];
    const float* b3     = (const float*)d_in[8];
    float* out          = (float*)d_out;

    const int B = in_sizes[1] / (NPTS * 3);   // 1024
    encoder_kernel<<<dim3(B), dim3(BDIM), 0, stream>>>(
        lg, coords, params, W1, b1, W2, b2, W3, b3, out);
}

// Round 3
// 37.660 us; speedup vs baseline: 1.6844x; 1.5485x over previous
//
#include <hip/hip_runtime.h>
#include <cfloat>

typedef unsigned long long ull;

constexpr int BDIM = 256;
constexpr int NPTS = 8192;
constexpr int KSEL = 16;
constexpr int PD_  = 16;
constexpr int DIN  = 20;
constexpr int HID  = 128;
constexpr int DOUT = 256;

__device__ __forceinline__ ull mkkey(float d, int n) {
    // positive-float bits are order-monotone; low 32 bits = index (tie-break)
    return ((ull)__float_as_uint(d) << 32) | (unsigned int)n;
}
__device__ __forceinline__ ull umin64(ull a, ull b) { return a < b ? a : b; }
__device__ __forceinline__ ull shflxor64(ull v, int m) {
    const int lo = __shfl_xor((int)(unsigned int)v, m, 64);
    const int hi = __shfl_xor((int)(v >> 32), m, 64);
    return ((ull)(unsigned int)hi << 32) | (unsigned int)lo;
}

__global__ __launch_bounds__(BDIM, 4) void encoder_kernel(
    const float* __restrict__ lg,      // (2,)
    const float* __restrict__ coords,  // (B, N, 3)
    const float* __restrict__ params,  // (B, N, 16)
    const float* __restrict__ W1, const float* __restrict__ b1,
    const float* __restrict__ W2, const float* __restrict__ b2,
    const float* __restrict__ W3, const float* __restrict__ b3,
    float* __restrict__ out)           // (B, 256)
{
    __shared__ ull   wmin[2][4];           // double-buffered per-wave minima
    __shared__ int   sel[KSEL];
    __shared__ float nb_par[KSEL][PD_ + 1];
    __shared__ float nb_xy[KSEL][2];
    __shared__ float xvec[DIN];
    __shared__ float h1[HID];
    __shared__ float h2[HID];

    const int b    = blockIdx.x;
    const int tid  = threadIdx.x;
    const int lane = tid & 63;
    const int wid  = tid >> 6;
    const float lg0 = lg[0];
    const float lg1 = lg[1];

    // ---- Phase 1: distances for 32 points/thread, f32 registers ----
    const float4* c4 = reinterpret_cast<const float4*>(coords + (size_t)b * NPTS * 3);

    float dd[32];
    #pragma unroll
    for (int it = 0; it < 8; ++it) {
        const int g = it * BDIM + tid;
        const float4 qa = c4[3 * g + 0];
        const float4 qb = c4[3 * g + 1];
        const float4 qc = c4[3 * g + 2];
        const float px[4] = {qa.x, qa.w, qb.z, qc.y};
        const float py[4] = {qa.y, qb.x, qb.w, qc.z};
        #pragma unroll
        for (int j = 0; j < 4; ++j) {
            // match numpy rounding: sub, sub, mul, mul, add — no fma contraction
            const float t0 = __fsub_rn(lg0, px[j]);
            const float t1 = __fsub_rn(lg1, py[j]);
            dd[it * 4 + j] = __fadd_rn(__fmul_rn(t0, t0), __fmul_rn(t1, t1));
        }
    }
    // global point index of slot (g, j): n = (g<<10) + (tid<<2) + j

    // ---- group minima (4 slots/group, 8 groups) + per-thread min ----
    ull g8[8];
    #pragma unroll
    for (int g = 0; g < 8; ++g) {
        const int nb = (g << 10) + (tid << 2);
        const ull a = umin64(mkkey(dd[4*g+0], nb+0), mkkey(dd[4*g+1], nb+1));
        const ull c = umin64(mkkey(dd[4*g+2], nb+2), mkkey(dd[4*g+3], nb+3));
        g8[g] = umin64(a, c);
    }
    ull lkey;
    {
        const ull t0 = umin64(g8[0], g8[1]);
        const ull t1 = umin64(g8[2], g8[3]);
        const ull t2 = umin64(g8[4], g8[5]);
        const ull t3 = umin64(g8[6], g8[7]);
        lkey = umin64(umin64(t0, t1), umin64(t2, t3));
    }

    // ---- Phase 2: top-16 via 16 x (wave butterfly + 4-way LDS min) ----
    unsigned int removed = 0u;
    for (int r = 0; r < KSEL; ++r) {
        ull w = lkey;
        #pragma unroll
        for (int m = 32; m > 0; m >>= 1) w = umin64(w, shflxor64(w, m));
        if (lane == 0) wmin[r & 1][wid] = w;
        __syncthreads();
        const ull wall = umin64(umin64(wmin[r & 1][0], wmin[r & 1][1]),
                                umin64(wmin[r & 1][2], wmin[r & 1][3]));
        const int wi = (int)(unsigned int)wall;   // winning global point index
        if (tid == 0) sel[r] = wi;
        if (((wi >> 2) & 255) == tid) {           // owner removes & rebuilds
            const int gw = wi >> 10;
            removed |= 1u << ((gw << 2) | (wi & 3));
            #pragma unroll
            for (int g = 0; g < 8; ++g) {
                if (g == gw) {                    // static indexing only
                    const int nb = (g << 10) + (tid << 2);
                    const ull k0 = (removed & (1u << (4*g+0))) ? ~0ull : mkkey(dd[4*g+0], nb+0);
                    const ull k1 = (removed & (1u << (4*g+1))) ? ~0ull : mkkey(dd[4*g+1], nb+1);
                    const ull k2 = (removed & (1u << (4*g+2))) ? ~0ull : mkkey(dd[4*g+2], nb+2);
                    const ull k3 = (removed & (1u << (4*g+3))) ? ~0ull : mkkey(dd[4*g+3], nb+3);
                    g8[g] = umin64(umin64(k0, k1), umin64(k2, k3));
                }
            }
            const ull t0 = umin64(g8[0], g8[1]);
            const ull t1 = umin64(g8[2], g8[3]);
            const ull t2 = umin64(g8[4], g8[5]);
            const ull t3 = umin64(g8[6], g8[7]);
            lkey = umin64(umin64(t0, t1), umin64(t2, t3));
        }
    }
    __syncthreads();

    // ---- Phase 3: coalesced gather of 16 neighbor rows, then means ----
    {
        const int k = tid >> 4, p = tid & 15;     // 256 threads = 16x16 cells
        nb_par[k][p] = params[((size_t)b * NPTS + sel[k]) * PD_ + p];
    }
    if (tid < 2 * KSEL) {
        const int k = tid >> 1, c = tid & 1;
        nb_xy[k][c] = coords[((size_t)b * NPTS + sel[k]) * 3 + c];
    }
    __syncthreads();
    if (tid < DIN) {
        float v;
        if (tid < 2) {
            v = lg[tid];
        } else if (tid < 4) {
            float s = 0.f;
            for (int k = 0; k < KSEL; ++k) s += nb_xy[k][tid - 2];
            v = s * (1.f / 16.f);
        } else {
            float s = 0.f;
            for (int k = 0; k < KSEL; ++k) s += nb_par[k][tid - 4];
            v = s * (1.f / 16.f);
        }
        xvec[tid] = v;
    }
    __syncthreads();

    // ---- Phase 4: MLP 20 -> 128 -> 128 -> 256 (fp32, weights L2-resident) ----
    if (tid < HID) {
        float acc = b1[tid];
        #pragma unroll
        for (int i = 0; i < DIN; ++i) acc = fmaf(xvec[i], W1[i * HID + tid], acc);
        h1[tid] = fmaxf(acc, 0.f);
    }
    __syncthreads();
    if (tid < HID) {
        float acc = b2[tid];
        #pragma unroll 16
        for (int i = 0; i < HID; ++i) acc = fmaf(h1[i], W2[i * HID + tid], acc);
        h2[tid] = fmaxf(acc, 0.f);
    }
    __syncthreads();
    {
        float acc = b3[tid];
        #pragma unroll 16
        for (int i = 0; i < HID; ++i) acc = fmaf(h2[i], W3[i * DOUT + tid], acc);
        out[(size_t)b * DOUT + tid] = acc;
    }
}

extern "C" void kernel_launch(void* const* d_in, const int* in_sizes, int n_in,
                              void* d_out, int out_size, void* d_ws, size_t ws_size,
                              hipStream_t stream) {
    const float* lg     = (const float*)d_in[0];
    const float* coords = (const float*)d_in[1];
    const float* params = (const float*)d_in[2];
    const float* W1     = (const float*)d_in[3];
    const float* b1     = (const float*)d_in[4];
    const float* W2     = (const float*)d_in[5];
    const float* b2     = (const float*)d_in[6];
    const float* W3     = (const float*)d_in[7];
    const float* b3     = (const float*)d_in[8];
    float* out          = (float*)d_out;

    const int B = in_sizes[1] / (NPTS * 3);   // 1024
    encoder_kernel<<<dim3(B), dim3(BDIM), 0, stream>>>(
        lg, coords, params, W1, b1, W2, b2, W3, b3, out);
}